// Round 1
// 8315.788 us; speedup vs baseline: 1.1146x; 1.1146x over previous
//
#include <hip/hip_runtime.h>
#include <math.h>

#define B_DIM   8192
#define N_DIM   784
#define NPAD    800          // 25*32, K/N pad for NN GEMM / Rbf
#define NROWS_W 1024         // 4*256, row-pad for Wbf (NT B operand, 256-wide n-tiles)
#define M_DIM   2048
#define XSZ     (B_DIM*N_DIM)
#define GSZ     (B_DIM*M_DIM)
#define NITER   50
#define PITER   100

typedef __attribute__((ext_vector_type(8))) short short8;
typedef __attribute__((ext_vector_type(4))) float floatx4;

// ---------------- async global->LDS (16B per lane, wave-uniform LDS base) ----------------
__device__ __forceinline__ void async_ld16(const unsigned short* g, unsigned short* l){
  __builtin_amdgcn_global_load_lds(
      (const __attribute__((address_space(1))) unsigned int*)g,
      (__attribute__((address_space(3))) unsigned int*)l,
      16, 0, 0);
}

// ---------------- threefry + erfinv (reproduce jax.random.normal(key(1),(1,2048))) ------------
__device__ __forceinline__ unsigned rotl32(unsigned x, int d){ return (x<<d)|(x>>(32-d)); }

__device__ void threefry2x32(unsigned& v0, unsigned& v1){
  const unsigned ks0=0u, ks1=1u, ks2=0x1BD11BDBu;
  unsigned x0=v0+ks0, x1=v1+ks1;
#define RND(R) { x0+=x1; x1=rotl32(x1,R); x1^=x0; }
  RND(13) RND(15) RND(26) RND(6)
  x0+=ks1; x1+=ks2+1u;
  RND(17) RND(29) RND(16) RND(24)
  x0+=ks2; x1+=ks0+2u;
  RND(13) RND(15) RND(26) RND(6)
  x0+=ks0; x1+=ks1+3u;
  RND(17) RND(29) RND(16) RND(24)
  x0+=ks1; x1+=ks2+4u;
  RND(13) RND(15) RND(26) RND(6)
  x0+=ks2; x1+=ks0+5u;
#undef RND
  v0=x0; v1=x1;
}

__device__ float erfinv_f(float x){
  float w = -logf((1.0f-x)*(1.0f+x));
  float p;
  if (w < 5.0f){
    w -= 2.5f;
    p = 2.81022636e-08f;
    p = fmaf(p,w, 3.43273939e-07f);
    p = fmaf(p,w,-3.5233877e-06f);
    p = fmaf(p,w,-4.39150654e-06f);
    p = fmaf(p,w, 0.00021858087f);
    p = fmaf(p,w,-0.00125372503f);
    p = fmaf(p,w,-0.00417768164f);
    p = fmaf(p,w, 0.246640727f);
    p = fmaf(p,w, 1.50140941f);
  } else {
    w = sqrtf(w) - 3.0f;
    p = -0.000200214257f;
    p = fmaf(p,w, 0.000100950558f);
    p = fmaf(p,w, 0.00134934322f);
    p = fmaf(p,w,-0.00367342844f);
    p = fmaf(p,w, 0.00573950773f);
    p = fmaf(p,w,-0.0076224613f);
    p = fmaf(p,w, 0.00943887047f);
    p = fmaf(p,w, 1.00167406f);
    p = fmaf(p,w, 2.83297682f);
  }
  return p*x;
}

__device__ float bits_to_normal(unsigned b){
  unsigned fb = (b>>9) | 0x3f800000u;
  float u01 = __uint_as_float(fb) - 1.0f;
  const float lo = -0.99999994f;
  float u = u01*(1.0f - lo) + lo;
  u = fmaxf(lo, u);
  return 1.41421356237f * erfinv_f(u);
}

__global__ void setup_kernel(float* __restrict__ xbuf0, float* __restrict__ accs){
  int i = threadIdx.x;   // 1024 threads
  if (i < 64) accs[i] = 0.0f;
  unsigned v0 = (unsigned)i, v1 = (unsigned)(1024+i);
  threefry2x32(v0, v1);
  xbuf0[i]        = bits_to_normal(v0);
  xbuf0[1024 + i] = bits_to_normal(v1);
}

// ---------------- bf16 convert helpers ----------------
__device__ __forceinline__ unsigned short f2bf(float f){
  unsigned u = __float_as_uint(f);
  unsigned r = (u + 0x7fffu + ((u>>16)&1u)) >> 16;
  return (unsigned short)r;
}
__device__ __forceinline__ unsigned pack2(float a, float b){
  return (unsigned)f2bf(a) | ((unsigned)f2bf(b) << 16);
}
__device__ __forceinline__ float bf2f(unsigned short s){
  return __uint_as_float(((unsigned)s) << 16);
}

// Wbf[j][k] = bf16(W[j][k]) : 1024 x 2048, rows >=784 zeroed
__global__ void conv_w(const float* __restrict__ W, unsigned short* __restrict__ Wbf){
  int i4 = (blockIdx.x*256 + threadIdx.x)*4;   // over 1024*2048 -> 2048 blocks
  int row = i4 >> 11;
  uint2 p = make_uint2(0,0);
  if (row < N_DIM){
    float4 v = *(const float4*)(W + (size_t)row*M_DIM + (i4 & 2047));
    p.x = pack2(v.x, v.y); p.y = pack2(v.z, v.w);
  }
  *(uint2*)(Wbf + i4) = p;
}

// Ybf[i][j] = bf16(Y[i][j]) : 8192 x 800, cols >=784 zeroed  (stored into Rbf buffer)
__global__ void conv_y(const float* __restrict__ Y, unsigned short* __restrict__ Ybf){
  int row = blockIdx.x;
  int c4 = threadIdx.x*4;
  if (c4 >= NPAD) return;
  uint2 p = make_uint2(0,0);
  if (c4 < N_DIM){
    float4 v = *(const float4*)(Y + (size_t)row*N_DIM + c4);
    p.x = pack2(v.x, v.y); p.y = pack2(v.z, v.w);
  }
  *(uint2*)(Ybf + (size_t)row*NPAD + c4) = p;
}

// WTbf[k][j] = bf16(W[j][k]) : 2048 x 800 (j in [784,800) -> 0)
__global__ void transpose_w(const float* __restrict__ W, unsigned short* __restrict__ WTbf){
  __shared__ float tile[32][33];
  int k0 = blockIdx.x*32;
  int j0 = blockIdx.y*32;
  int tx = threadIdx.x & 31, ty = threadIdx.x >> 5;
#pragma unroll
  for (int i=0;i<4;i++){
    int j = j0 + ty + 8*i;
    float v = (j < N_DIM) ? W[(size_t)j*M_DIM + k0 + tx] : 0.0f;
    tile[tx][ty+8*i] = v;
  }
  __syncthreads();
#pragma unroll
  for (int i=0;i<4;i++){
    int k = k0 + ty + 8*i;
    WTbf[(size_t)k*NPAD + j0 + tx] = f2bf(tile[ty+8*i][tx]);
  }
}

// ---------------- Q = W^T W (fp32 VALU GEMM, one-time, power-method only) ----------------
__global__ __launch_bounds__(256)
void compute_q(const float* __restrict__ W, float* __restrict__ Q){
  __shared__ float As2[16][132];
  __shared__ float Bs2[16][132];
  const int t = threadIdx.x;
  const int a0 = blockIdx.x*128, b0 = blockIdx.y*128;
  const int ty = t>>4, tx = t&15;
  float acc[8][8];
#pragma unroll
  for (int i=0;i<8;i++)
#pragma unroll
    for (int j=0;j<8;j++) acc[i][j]=0.0f;

  for (int j0=0; j0<N_DIM; j0+=16){
#pragma unroll
    for (int h=0; h<8; ++h){
      int idx = h*256 + t;
      int r = idx>>7, c = idx&127;
      As2[r][c] = W[(size_t)(j0+r)*M_DIM + a0 + c];
      Bs2[r][c] = W[(size_t)(j0+r)*M_DIM + b0 + c];
    }
    __syncthreads();
#pragma unroll
    for (int kk=0; kk<16; ++kk){
      float a[8], b[8];
#pragma unroll
      for (int i=0;i<8;i++) a[i] = As2[kk][ty*8+i];
#pragma unroll
      for (int j=0;j<8;j++) b[j] = Bs2[kk][tx*8+j];
#pragma unroll
      for (int i=0;i<8;i++)
#pragma unroll
        for (int j=0;j<8;j++) acc[i][j] = fmaf(a[i], b[j], acc[i][j]);
    }
    __syncthreads();
  }
#pragma unroll
  for (int i=0;i<8;i++){
    int a = a0 + ty*8 + i;
#pragma unroll
    for (int j=0;j<8;j++) Q[(size_t)a*M_DIM + b0 + tx*8 + j] = acc[i][j];
  }
}

// ---------------- reductions ----------------
__global__ void sumsq_kernel(const float* __restrict__ v, int n, float* __restrict__ acc){
  __shared__ float red[256];
  int t = threadIdx.x;
  float s = 0.0f;
  for (int i = blockIdx.x*256 + t; i < n; i += gridDim.x*256){ float x = v[i]; s = fmaf(x,x,s); }
  red[t] = s; __syncthreads();
  for (int off=128; off>0; off>>=1){ if (t<off) red[t]+=red[t+off]; __syncthreads(); }
  if (t==0) atomicAdd(acc, red[0]);
}

// ---------------- power method on Q (symmetric) ----------------
__global__ void pm_q(const float* __restrict__ x, const float* __restrict__ Q,
                     float* __restrict__ xout){
  __shared__ float red[256];
  int t = threadIdx.x;
  float s = 0.0f;
  for (int k=t; k<M_DIM; k+=256){ float v = x[k]; s = fmaf(v,v,s); }
  red[t]=s; __syncthreads();
  for (int off=128; off>0; off>>=1){ if (t<off) red[t]+=red[t+off]; __syncthreads(); }
  float inv = 1.0f/sqrtf(red[0]);
  int wave = t>>6, lane = t&63;
  int j = blockIdx.x*4 + wave;
  const float* Qr = Q + (size_t)j*M_DIM;
  float acc = 0.0f;
  for (int k=lane; k<M_DIM; k+=64) acc = fmaf(x[k], Qr[k], acc);
  for (int off=32; off>0; off>>=1) acc += __shfl_down(acc, off);
  if (lane==0) xout[j] = acc * inv;
}

// params: [0]=c, [1]=eta=1/c, [2]=lam/c, [3]=||Y||
__global__ void finish_power(const float* __restrict__ xfin, const float* __restrict__ accs,
                             float* __restrict__ params){
  __shared__ float red[256];
  int t = threadIdx.x;
  float s = 0.0f;
  for (int k=t; k<M_DIM; k+=256){ float v = xfin[k]; s = fmaf(v,v,s); }
  red[t]=s; __syncthreads();
  for (int off=128; off>0; off>>=1){ if (t<off) red[t]+=red[t+off]; __syncthreads(); }
  if (t==0){
    float c = sqrtf(red[0]);
    params[0] = c;
    params[1] = 1.0f/c;
    params[2] = 0.1f/c;
    params[3] = sqrtf(accs[0]);
  }
}

__device__ __forceinline__ float softthr(float v, float th){
  float a = fmaxf(fabsf(v) - th, 0.0f);
  return copysignf(a, v);
}

// ================= MFMA GEMM NT: C[i,j] = sum_k A[i,k]*B[j,k] =================
// Tile 64x256. Grid 512 (1D, XCD-swizzled: XCD g8 owns a 16m x 4n panel).
// 2-phase double-buffered K-loop: prefetch k+1 tile (global_load_lds) issued BEFORE the
// ds_read+MFMA of tile k; single barrier per K-step (its implicit vmcnt(0) drains the
// prefetch, whose latency was hidden under the MFMAs).
// A = Zhi bf16 [8192 x 2048], B = Wbf bf16 [1024 x 2048] (rows>=784 zero).
// MODE 0: R = A*B^T - Y -> Rbf (bf16, stride NPAD, cols [784,800) zeroed), ||R||^2 -> nacc.
// MODE 1: X = A*B^T (fp32 out; A holds bf16 of final Gamma).
template<int MODE>
__global__ __launch_bounds__(256)
void mfma_nt(const unsigned short* __restrict__ Abf,
             const unsigned short* __restrict__ Bbf,
             const float* __restrict__ Y,
             unsigned short* __restrict__ Rbf,
             float* __restrict__ X,
             float* __restrict__ nacc){
  __shared__ float4 smem4[2560];                 // 40 KB: (As 4KB + Bs 16KB) x2
  unsigned short* As0 = (unsigned short*)smem4;  // [64 x 32]
  unsigned short* Bs0 = As0 + 64*32;             // [256 x 32]
  unsigned short* As1 = Bs0 + 256*32;
  unsigned short* Bs1 = As1 + 64*32;
  float* fbuf = (float*)smem4;                   // [64 x 68] fp32 epilogue chunk (17.4 KB)

  const int bid = blockIdx.x;
  const int g8  = bid & 7, w = bid >> 3;         // XCD panel: 16m x 4n
  const int m0  = (g8*16 + (w>>2))*64;
  const int n0  = (w & 3)*256;

  const int t    = threadIdx.x;
  const int wave = t>>6, lane = t&63;
  const int wm2  = wave>>1, wn2 = wave&1;        // 2x2 waves over 64x256
  const int quad = lane>>4, l15 = lane&15;
  const int lrow = lane>>2;
  const int lk   = (lane&3)*8;

  floatx4 acc[2][8];
#pragma unroll
  for (int i=0;i<2;i++)
#pragma unroll
    for (int j=0;j<8;j++) acc[i][j] = (floatx4)(0.0f);

  auto stage = [&](unsigned short* As, unsigned short* Bs, int k0){
    // A: 64x32 = 4 chunks of 16 rows; one async per wave
    async_ld16(Abf + (size_t)(m0 + wave*16 + lrow)*M_DIM + k0 + lk, &As[wave*512]);
    // B: 256x32 = 16 chunks; 4 per wave
#pragma unroll
    for (int c=0; c<4; ++c){
      int chunk = wave*4 + c;
      async_ld16(Bbf + (size_t)(n0 + chunk*16 + lrow)*M_DIM + k0 + lk, &Bs[chunk*512]);
    }
  };

  stage(As0, Bs0, 0);
  __syncthreads();
  int cur = 0;
  for (int k0=0; k0<M_DIM; k0+=32, cur^=1){
    unsigned short* As = cur ? As1 : As0;
    unsigned short* Bs = cur ? Bs1 : Bs0;
    if (k0+32 < M_DIM) stage(cur ? As0 : As1, cur ? Bs0 : Bs1, k0+32);
    short8 af[2], bfr[8];
#pragma unroll
    for (int ti=0; ti<2; ++ti)
      af[ti] = *(const short8*)&As[(wm2*32 + ti*16 + l15)*32 + quad*8];
#pragma unroll
    for (int tj=0; tj<8; ++tj)
      bfr[tj] = *(const short8*)&Bs[(wn2*128 + tj*16 + l15)*32 + quad*8];
#pragma unroll
    for (int ti=0; ti<2; ++ti)
#pragma unroll
      for (int tj=0; tj<8; ++tj)
        acc[ti][tj] = __builtin_amdgcn_mfma_f32_16x16x32_bf16(af[ti], bfr[tj], acc[ti][tj], 0, 0, 0);
    __syncthreads();
  }

  // ---- coalesced epilogue: 4 chunks of [64 rows x 64 cols] via LDS (stride 68, 16B-aligned) ----
  float ss = 0.0f;
#pragma unroll
  for (int c=0; c<4; ++c){
    if (wn2 == (c>>1)){
      int tb = (c&1)*4;
#pragma unroll
      for (int ti=0; ti<2; ++ti)
#pragma unroll
        for (int u=0; u<4; ++u)
#pragma unroll
          for (int r=0; r<4; ++r)
            fbuf[(wm2*32 + ti*16 + quad*4 + r)*68 + u*16 + l15] = acc[ti][tb+u][r];
    }
    __syncthreads();
#pragma unroll
    for (int k=0; k<4; ++k){
      int row = k*16 + (t>>4);
      int col = (t&15)*4;
      int m = m0 + row;
      int n = n0 + c*64 + col;
      float4 v = *(const float4*)&fbuf[row*68 + col];
      if (MODE==0){
        if (n < N_DIM){
          float4 yv = *(const float4*)(Y + (size_t)m*N_DIM + n);
          float r0 = v.x - yv.x, r1 = v.y - yv.y, r2 = v.z - yv.z, r3 = v.w - yv.w;
          uint2 p; p.x = pack2(r0, r1); p.y = pack2(r2, r3);
          *(uint2*)(Rbf + (size_t)m*NPAD + n) = p;
          ss = fmaf(r0,r0, fmaf(r1,r1, fmaf(r2,r2, fmaf(r3,r3, ss))));
        } else if (n < NPAD){
          *(uint2*)(Rbf + (size_t)m*NPAD + n) = make_uint2(0,0);
        }
      } else {
        if (n < N_DIM) *(float4*)(X + (size_t)m*N_DIM + n) = v;
      }
    }
    __syncthreads();
  }

  if (MODE==0){
    for (int off=32; off>0; off>>=1) ss += __shfl_down(ss, off);
    if (lane==0) atomicAdd(nacc, ss);
  }
}

// ================= MFMA GEMM NN: G[i,n] = sum_j A[i,j]*WT[n,j] ==========
// Tile 128x128. Grid 1024 (1D, XCD-swizzled: XCD g8 owns an 8m x 16n panel -> its 1024-row
// A-slab (1.6 MB) + all of WTbf (3.3 MB) are XCD-L2-resident).
// 2-phase double-buffered K-loop (see mfma_nt). __launch_bounds__(256,3) keeps >=3 waves/SIMD
// so grid 1024 translates into 3-4 blocks/CU (was grid-capped at 2, 22.7% occupancy).
// A = Rbf/Ybf [8192 x 800] (async), B = WTbf [2048 x 800] (async).
// State: z as hi/lo bf16 pair; Gamma fp32 (graded output).
// MODE 0 (init, A=Ybf): g=soft(eta*G,0.1); Gamma=g; z=g -> hi/lo.
// MODE 1 (iter, A=Rbf): z=hi+lo; g=soft(z-eta*G,lam/c); zn=g+mu*(g-go); store hi/lo.
// MODE 2 (last iter):   g=soft(z-eta*G,lam/c); Gamma=g; Zhi=bf16(g) [A for final X GEMM].
template<int MODE>
__global__ __launch_bounds__(256,3)
void mfma_nn(const unsigned short* __restrict__ Abf,
             const unsigned short* __restrict__ WTbf,
             float* __restrict__ Gamma,
             unsigned short* __restrict__ Zhi,
             unsigned short* __restrict__ Zlo,
             const float* __restrict__ params,
             float mu){
  __shared__ float4 smem4[2048];                 // 32 KB: (As 8KB + Bs 8KB) x2
  unsigned short* As0 = (unsigned short*)smem4;  // [128 x 32]
  unsigned short* Bs0 = As0 + 128*32;            // [128 x 32]
  unsigned short* As1 = Bs0 + 128*32;
  unsigned short* Bs1 = As1 + 128*32;
  float* fbuf = (float*)smem4;                   // [128 x 36] fp32 epilogue chunk (18 KB)

  const int bid = blockIdx.x;
  const int g8  = bid & 7, w = bid >> 3;         // XCD panel: 8m x 16n
  const int m0  = (g8*8 + (w>>4))*128;
  const int n0  = (w & 15)*128;

  const int t    = threadIdx.x;
  const int wave = t>>6, lane = t&63;
  const int wm   = wave>>1, wn = wave&1;         // 2x2 waves over 128x128
  const int quad = lane>>4, l15 = lane&15;
  const int lrow = lane>>2;
  const int lk   = (lane&3)*8;

  floatx4 acc[4][4];
#pragma unroll
  for (int i=0;i<4;i++)
#pragma unroll
    for (int j=0;j<4;j++) acc[i][j] = (floatx4)(0.0f);

  auto stage = [&](unsigned short* As, unsigned short* Bs, int k0){
    // A: 128x32 = 8 chunks of 16 rows; 2 per wave.  B: same.
#pragma unroll
    for (int c=0; c<2; ++c){
      int chunk = wave*2 + c;
      async_ld16(Abf  + (size_t)(m0 + chunk*16 + lrow)*NPAD + k0 + lk, &As[chunk*512]);
      async_ld16(WTbf + (size_t)(n0 + chunk*16 + lrow)*NPAD + k0 + lk, &Bs[chunk*512]);
    }
  };

  stage(As0, Bs0, 0);
  __syncthreads();
  int cur = 0;
  for (int k0=0; k0<NPAD; k0+=32, cur^=1){
    unsigned short* As = cur ? As1 : As0;
    unsigned short* Bs = cur ? Bs1 : Bs0;
    if (k0+32 < NPAD) stage(cur ? As0 : As1, cur ? Bs0 : Bs1, k0+32);
    short8 af[4], bfr[4];
#pragma unroll
    for (int ti=0; ti<4; ++ti)
      af[ti] = *(const short8*)&As[(wm*64 + ti*16 + l15)*32 + quad*8];
#pragma unroll
    for (int tj=0; tj<4; ++tj)
      bfr[tj] = *(const short8*)&Bs[(wn*64 + tj*16 + l15)*32 + quad*8];
#pragma unroll
    for (int ti=0; ti<4; ++ti)
#pragma unroll
      for (int tj=0; tj<4; ++tj)
        acc[ti][tj] = __builtin_amdgcn_mfma_f32_16x16x32_bf16(af[ti], bfr[tj], acc[ti][tj], 0, 0, 0);
    __syncthreads();
  }

  const float eta  = params[1];
  const float lamc = params[2];

  // ---- coalesced epilogue: 4 chunks of [128 rows x 32 cols] via LDS (stride 36) ----
  // All 12 global loads of a chunk are issued before any use (explicit ILP batch).
#pragma unroll
  for (int c=0; c<4; ++c){
    if (wn == (c>>1)){
      int tb = (c&1)*2;
#pragma unroll
      for (int ti=0; ti<4; ++ti)
#pragma unroll
        for (int u=0; u<2; ++u)
#pragma unroll
          for (int r=0; r<4; ++r)
            fbuf[(wm*64 + ti*16 + quad*4 + r)*36 + u*16 + l15] = acc[ti][tb+u][r];
    }
    __syncthreads();
    const int rbase = t>>3;
    const int col   = (t&7)*4;
    const int n     = n0 + c*32 + col;
    size_t idx[4];
    uint2 ph[4], pl[4];
    float4 gov[4];
#pragma unroll
    for (int k=0; k<4; ++k){
      int m = m0 + k*32 + rbase;
      idx[k] = (size_t)m*M_DIM + n;
      if (MODE!=0){
        ph[k] = *(const uint2*)(Zhi + idx[k]);
        pl[k] = *(const uint2*)(Zlo + idx[k]);
      }
      if (MODE==1) gov[k] = *(const float4*)(Gamma + idx[k]);
    }
#pragma unroll
    for (int k=0; k<4; ++k){
      int row = k*32 + rbase;
      float4 g4 = *(const float4*)&fbuf[row*36 + col];
      float gr[4] = {g4.x, g4.y, g4.z, g4.w};
      if (MODE!=0){
        unsigned short h[4] = {(unsigned short)(ph[k].x&0xffff),(unsigned short)(ph[k].x>>16),
                               (unsigned short)(ph[k].y&0xffff),(unsigned short)(ph[k].y>>16)};
        unsigned short l[4] = {(unsigned short)(pl[k].x&0xffff),(unsigned short)(pl[k].x>>16),
                               (unsigned short)(pl[k].y&0xffff),(unsigned short)(pl[k].y>>16)};
#pragma unroll
        for (int e=0;e<4;e++){
          float zv = bf2f(h[e]) + bf2f(l[e]);
          gr[e] = softthr(zv - eta*gr[e], lamc);
        }
      } else {
#pragma unroll
        for (int e=0;e<4;e++) gr[e] = softthr(eta*gr[e], 0.1f);
      }
      *(float4*)(Gamma + idx[k]) = make_float4(gr[0],gr[1],gr[2],gr[3]);
      if (MODE==1){
        float go0 = gov[k].x, go1 = gov[k].y, go2 = gov[k].z, go3 = gov[k].w;
        float zn[4];
        zn[0] = gr[0] + mu*(gr[0] - go0);
        zn[1] = gr[1] + mu*(gr[1] - go1);
        zn[2] = gr[2] + mu*(gr[2] - go2);
        zn[3] = gr[3] + mu*(gr[3] - go3);
        unsigned short h0=f2bf(zn[0]), h1=f2bf(zn[1]), h2=f2bf(zn[2]), h3=f2bf(zn[3]);
        uint2 phx; phx.x = (unsigned)h0 | ((unsigned)h1<<16); phx.y = (unsigned)h2 | ((unsigned)h3<<16);
        uint2 plx; plx.x = pack2(zn[0]-bf2f(h0), zn[1]-bf2f(h1));
                   plx.y = pack2(zn[2]-bf2f(h2), zn[3]-bf2f(h3));
        *(uint2*)(Zhi + idx[k]) = phx;
        *(uint2*)(Zlo + idx[k]) = plx;
      } else if (MODE==0){
        unsigned short h0=f2bf(gr[0]), h1=f2bf(gr[1]), h2=f2bf(gr[2]), h3=f2bf(gr[3]);
        uint2 phx; phx.x = (unsigned)h0 | ((unsigned)h1<<16); phx.y = (unsigned)h2 | ((unsigned)h3<<16);
        uint2 plx; plx.x = pack2(gr[0]-bf2f(h0), gr[1]-bf2f(h1));
                   plx.y = pack2(gr[2]-bf2f(h2), gr[3]-bf2f(h3));
        *(uint2*)(Zhi + idx[k]) = phx;
        *(uint2*)(Zlo + idx[k]) = plx;
      } else {
        uint2 phx; phx.x = pack2(gr[0], gr[1]); phx.y = pack2(gr[2], gr[3]);
        *(uint2*)(Zhi + idx[k]) = phx;
      }
    }
    __syncthreads();
  }
}

__global__ void norms_finalize(const float* __restrict__ nacc, const float* __restrict__ params,
                               float* __restrict__ out){
  int i = threadIdx.x;
  if (i < NITER) out[i] = sqrtf(nacc[i]) / params[3];
}

extern "C" void kernel_launch(void* const* d_in, const int* in_sizes, int n_in,
                              void* d_out, int out_size, void* d_ws, size_t ws_size,
                              hipStream_t stream){
  const float* Y  = (const float*)d_in[0];
  const float* W  = (const float*)d_in[1];
  float* out      = (float*)d_out;
  float* X        = out;
  float* Gamma    = out + XSZ;
  float* norms    = out + XSZ + GSZ;

  // ---- all scratch in ws (~105 MB; ws proven >= 134 MB in round 6) ----
  unsigned short* Zhi  = (unsigned short*)d_ws;            // [8192x2048] 33.55 MB
  unsigned short* Zlo  = Zhi  + (size_t)GSZ;               // [8192x2048] 33.55 MB
  unsigned short* Rbf  = Zlo  + (size_t)GSZ;               // [8192x800]  13.11 MB (Ybf at init)
  unsigned short* Wbf  = Rbf  + (size_t)B_DIM*NPAD;        // [1024x2048]  4.19 MB
  unsigned short* WTbf = Wbf  + (size_t)NROWS_W*M_DIM;     // [2048x800]   3.28 MB
  float* Q      = (float*)(WTbf + (size_t)M_DIM*NPAD);     // [2048x2048] 16.78 MB
  float* xb0    = Q + (size_t)M_DIM*M_DIM;
  float* xb1    = xb0 + M_DIM;
  float* params = xb1 + M_DIM;
  float* accs   = params + 8;    // accs[0]=||Y||^2, accs[1..50]=per-iter ||R||^2

  setup_kernel<<<dim3(1), dim3(1024), 0, stream>>>(xb0, accs);
  sumsq_kernel<<<dim3(512), dim3(256), 0, stream>>>(Y, XSZ, accs);
  conv_w      <<<dim3(2048), dim3(256), 0, stream>>>(W, Wbf);
  transpose_w <<<dim3(64,25), dim3(256), 0, stream>>>(W, WTbf);
  conv_y      <<<dim3(B_DIM), dim3(256), 0, stream>>>(Y, Rbf);   // Rbf := Ybf for init GEMM

  compute_q<<<dim3(16,16), dim3(256), 0, stream>>>(W, Q);
  float* xa = xb0; float* xc = xb1;
  for (int it=0; it<PITER; ++it){
    pm_q<<<dim3(512), dim3(256), 0, stream>>>(xa, Q, xc);
    float* tmp = xa; xa = xc; xc = tmp;
  }
  finish_power<<<dim3(1), dim3(256), 0, stream>>>(xa, accs, params);

  // Gamma0 = soft(eta*(Y@W), 0.1); z0 = Gamma0 -> hi/lo
  mfma_nn<0><<<dim3(1024), dim3(256), 0, stream>>>(Rbf, WTbf, Gamma, Zhi, Zlo, params, 0.0f);

  float tcur = 1.0f;
  for (int it=0; it<NITER; ++it){
    mfma_nt<0><<<dim3(512), dim3(256), 0, stream>>>(Zhi, Wbf, Y, Rbf, nullptr, accs + 1 + it);
    float tsq = tcur*tcur;
    float tn  = (1.0f + sqrtf(1.0f + 4.0f*tsq)) / 2.0f;
    float mu  = (tcur - 1.0f) / tn;
    tcur = tn;
    if (it < NITER-1)
      mfma_nn<1><<<dim3(1024), dim3(256), 0, stream>>>(Rbf, WTbf, Gamma, Zhi, Zlo, params, mu);
    else
      mfma_nn<2><<<dim3(1024), dim3(256), 0, stream>>>(Rbf, WTbf, Gamma, Zhi, Zlo, params, mu);
  }

  norms_finalize<<<dim3(1), dim3(64), 0, stream>>>(accs + 1, params, norms);

  // X = Gamma @ W^T  (Zhi holds bf16 Gamma; Wbf in ws -> no aliasing, async B path)
  mfma_nt<1><<<dim3(512), dim3(256), 0, stream>>>(Zhi, Wbf, nullptr, nullptr, X, nullptr);
}